// Round 2
// baseline (125.988 us; speedup 1.0000x reference)
//
#include <hip/hip_runtime.h>
#include <math.h>

// SphereInterLoss: exact 10-NN via x-sorted pruning.
//  rank_kernel: counting-rank by x -> sidx (sorted permutation), per batch.
//  knn_kernel : stage sorted cloud in LDS; block = 64 consecutive sorted
//               queries (lane = query); 4 waves scan interleaved chunk
//               classes outward from the queries' own chunk; prune a
//               direction when gap_x^2 > shared upper bound on the 11th
//               smallest d2 (valid: every wave's k[10] >= global t11;
//               +1 ulp@2^-12 bump covers key truncation).
//  Selection: branchless sorted insert via v_med3_f32 on float keys
//  (d2 bits & ~0xFFF) | sorted_idx. Self d2 == exact 0 -> key == idx
//  (denormal) -> always k[0] after merge -> dropped.

#define NB 8
#define NN 4096
#define QPB 64
#define WAVES 4
#define NCH 64          // chunks of 64 sorted points per batch

__device__ __forceinline__ float med3f(float a, float b, float c) {
#if defined(__has_builtin) && __has_builtin(__builtin_amdgcn_fmed3f)
    return __builtin_amdgcn_fmed3f(a, b, c);
#else
    float d;
    asm("v_med3_f32 %0, %1, %2, %3" : "=v"(d) : "v"(a), "v"(b), "v"(c));
    return d;
#endif
}

__device__ __forceinline__ void insert11(float k[11], float u) {
#pragma unroll
    for (int j = 10; j >= 1; --j) k[j] = med3f(k[j - 1], k[j], u);
    k[0] = fminf(k[0], u);
}

__device__ __forceinline__ float waveMaxF(float v) {
#pragma unroll
    for (int o = 32; o > 0; o >>= 1) v = fmaxf(v, __shfl_xor(v, o, 64));
    return v;
}

// counting-rank by x: sidx[b][rank] = original index
__global__ __launch_bounds__(256) void rank_kernel(const float4* __restrict__ sp_all,
                                                   int* __restrict__ sidx) {
    __shared__ float xs[NN];
    __shared__ int pc[QPB][WAVES];
    const int b = blockIdx.x >> 6, ech = blockIdx.x & 63;
    const int tid = threadIdx.x, lane = tid & 63, seg = tid >> 6;
    const float* spf = (const float*)(sp_all + (size_t)b * NN);
    for (int i = tid; i < NN; i += 256) xs[i] = spf[4 * i];
    __syncthreads();
    const int e = ech * 64 + lane;
    const float xe = xs[e];
    int cnt = 0;
    const int base = seg * (NN / WAVES);
    for (int j = base; j < base + NN / WAVES; ++j) {
        float xj = xs[j];
        cnt += (int)((xj < xe) || (xj == xe && j < e));
    }
    pc[lane][seg] = cnt;
    __syncthreads();
    if (seg == 0) {
        int rank = pc[lane][0] + pc[lane][1] + pc[lane][2] + pc[lane][3];
        sidx[b * NN + rank] = e;
    }
}

__global__ __launch_bounds__(256, 2)
void knn_kernel(const float4* __restrict__ sp_all, const int* __restrict__ sidx,
                float* __restrict__ top_dist) {
    __shared__ float4 c4[NN];                 // sorted {x,y,z,|c|^2}  64 KB
    __shared__ float mrg[QPB][WAVES][11];     // 11 KB
    volatile __shared__ float sT[QPB][WAVES]; // shared k[10] bounds, 1 KB

    const int b  = blockIdx.x >> 6;
    const int c0 = blockIdx.x & 63;           // this block's sorted chunk
    const int tid = threadIdx.x, lane = tid & 63, s = tid >> 6;
    const float4* sp = sp_all + (size_t)b * NN;
    const float* spf = (const float*)sp;
    const int* si = sidx + b * NN;

    for (int i = tid; i < NN; i += 256) {     // gather-stage sorted cloud
        float4 v = sp[si[i]];
        v.w = fmaf(v.x, v.x, fmaf(v.y, v.y, v.z * v.z));
        c4[i] = v;
    }
    sT[lane][s] = __builtin_inff();
    __syncthreads();

    const int qbase = c0 * 64;
    const float4 q = c4[qbase + lane];
    const float xqlo = c4[qbase].x, xqhi = c4[qbase + 63].x;

    float k[11];
#pragma unroll
    for (int j = 0; j < 11; ++j) k[j] = __builtin_inff();

    auto scan_chunk = [&](int c) {
        const int base = c * 64;
#pragma unroll 4
        for (int i = 0; i < 64; ++i) {
            float4 cc = c4[base + i];
            float dot = fmaf(q.x, cc.x, fmaf(q.y, cc.y, q.z * cc.z));
            float d2  = fmaxf(fmaf(-2.0f, dot, q.w + cc.w), 0.0f);
            unsigned u = (__float_as_uint(d2) & 0xFFFFF000u) | (unsigned)(base + i);
            insert11(k, __uint_as_float(u));
        }
        sT[lane][s] = k[10];
    };

    int cR = c0 + ((s - c0) & 3);             // nearest chunk of class s, right
    int cL = cR - 4;
    bool goR = (cR < NCH), goL = (cL >= 0);

    while (goR || goL) {
        // upper bound on every lane-query's true 11th-smallest d2:
        // min over waves of published k[10], max over lanes, +1 trunc step.
        float bnd = fminf(fminf(sT[lane][0], sT[lane][1]),
                          fminf(sT[lane][2], sT[lane][3]));
        float T = __uint_as_float(__float_as_uint(waveMaxF(bnd)) + 0x1000u);
        if (goR) {
            float gap = c4[cR * 64].x - xqhi;
            if (gap > 0.0f && gap * gap > T) goR = false;
            else { scan_chunk(cR); cR += 4; goR = (cR < NCH); }
        }
        if (goL) {
            float gap = xqlo - c4[cL * 64 + 63].x;
            if (gap > 0.0f && gap * gap > T) goL = false;
            else { scan_chunk(cL); cL -= 4; goL = (cL >= 0); }
        }
    }

#pragma unroll
    for (int j = 0; j < 11; ++j) mrg[lane][s][j] = k[j];
    __syncthreads();

    if (s == 0) {
#pragma unroll
        for (int sg = 1; sg < WAVES; ++sg)
#pragma unroll
            for (int j = 0; j < 11; ++j) insert11(k, mrg[lane][sg][j]);

        // k[0] is self (exact d2 == 0). Evaluate k[1..10].
        const int qs = qbase + lane;
        const int oin = si[qs];
        const float rn = spf[4 * oin + 3];
        float best = 1e30f;
#pragma unroll
        for (int j = 1; j <= 10; ++j) {
            int m = (int)(__float_as_uint(k[j]) & 0xFFFu);
            float4 cc = c4[m];
            float dx = q.x - cc.x, dy = q.y - cc.y, dz = q.z - cc.z;
            float dis = sqrtf(fmaf(dx, dx, fmaf(dy, dy, dz * dz)));
            float rm = spf[4 * si[m] + 3];
            best = fminf(best, dis - (rn + rm));
        }
        top_dist[b * NN + oin] = best;
    }
}

// per-batch variance (ddof=1), two-pass
__global__ void var_kernel(const float* __restrict__ td, float* __restrict__ vars) {
    __shared__ float red[256];
    const int b = blockIdx.x, t = threadIdx.x;
    const float* x = td + b * NN;

    float ssum = 0.0f;
    for (int i = t; i < NN; i += 256) ssum += x[i];
    red[t] = ssum;
    __syncthreads();
    for (int o = 128; o > 0; o >>= 1) {
        if (t < o) red[t] += red[t + o];
        __syncthreads();
    }
    const float mu = red[0] / (float)NN;
    __syncthreads();

    float ss = 0.0f;
    for (int i = t; i < NN; i += 256) {
        float d = x[i] - mu;
        ss = fmaf(d, d, ss);
    }
    red[t] = ss;
    __syncthreads();
    for (int o = 128; o > 0; o >>= 1) {
        if (t < o) red[t] += red[t + o];
        __syncthreads();
    }
    if (t == 0) vars[b] = red[0] / (float)(NN - 1);
}

__global__ void fin_kernel(const float* __restrict__ vars, float* __restrict__ out) {
    if (threadIdx.x == 0) {
        float sum = 0.0f;
        for (int b = 0; b < NB; ++b) sum += vars[b];
        out[0] = sum / (float)NB;
    }
}

extern "C" void kernel_launch(void* const* d_in, const int* in_sizes, int n_in,
                              void* d_out, int out_size, void* d_ws, size_t ws_size,
                              hipStream_t stream) {
    const float4* spheres = (const float4*)d_in[0];
    int*   sidx = (int*)d_ws;                                  // [NB*NN]
    float* td   = (float*)((char*)d_ws + (size_t)NB * NN * sizeof(int)); // [NB*NN]
    float* vars = td + NB * NN;                                // [NB]
    float* out  = (float*)d_out;

    rank_kernel<<<dim3(NB * (NN / QPB)), dim3(256), 0, stream>>>(spheres, sidx);
    knn_kernel<<<dim3(NB * (NN / QPB)), dim3(256), 0, stream>>>(spheres, sidx, td);
    var_kernel<<<dim3(NB), dim3(256), 0, stream>>>(td, vars);
    fin_kernel<<<dim3(1), dim3(64), 0, stream>>>(vars, out);
}

// Round 3
// 102.270 us; speedup vs baseline: 1.2319x; 1.2319x over previous
//
#include <hip/hip_runtime.h>
#include <math.h>

// SphereInterLoss: exact 10-NN via x-sorted pruning, round 3.
//  memset(rank=0) -> rank_kernel (tiled pairwise count, u64 keys, atomic
//  partials) -> scatter_kernel (sorted4 {x,y,z,|c|^2} + u16 perm) ->
//  knn_kernel (8-wave candidate split, shared LDS chunk counter in
//  nearest-first ring order, shared pruning bound) -> var -> fin.

#define NB 8
#define NN 4096
#define NCH 64          // 64-point chunks per batch

__device__ __forceinline__ float med3f(float a, float b, float c) {
    return __builtin_amdgcn_fmed3f(a, b, c);
}

// insert u into ascending k[0..10], dropping the max (branchless).
__device__ __forceinline__ void insert11(float k[11], float u) {
#pragma unroll
    for (int j = 10; j >= 1; --j) k[j] = med3f(k[j - 1], k[j], u);
    k[0] = fminf(k[0], u);
}

// ---------------- rank: exact x-rank via pairwise counting ----------------
// grid 8 batches x 16 e-tiles x 8 j-tiles = 1024 blocks, 256 thr.
__global__ __launch_bounds__(256)
void rank_kernel(const float4* __restrict__ sp, int* __restrict__ rank) {
    __shared__ unsigned long long keys[512];
    const int blk = blockIdx.x;
    const int b = blk >> 7, et = (blk >> 3) & 15, jt = blk & 7;
    const float4* spb = sp + ((size_t)b << 12);
    const int j0 = jt * 512;
    for (int j = threadIdx.x; j < 512; j += 256) {
        unsigned u = __float_as_uint(spb[j0 + j].x);
        u = (u >> 31) ? ~u : (u | 0x80000000u);
        keys[j] = ((unsigned long long)u << 12) | (unsigned)(j0 + j);
    }
    __syncthreads();
    const int e = et * 256 + threadIdx.x;
    unsigned ue = __float_as_uint(spb[e].x);
    ue = (ue >> 31) ? ~ue : (ue | 0x80000000u);
    const unsigned long long ke = ((unsigned long long)ue << 12) | (unsigned)e;
    int c0 = 0, c1 = 0, c2 = 0, c3 = 0;
    for (int j = 0; j < 512; j += 4) {
        c0 += (keys[j]     < ke);
        c1 += (keys[j + 1] < ke);
        c2 += (keys[j + 2] < ke);
        c3 += (keys[j + 3] < ke);
    }
    atomicAdd(&rank[(b << 12) + e], c0 + c1 + c2 + c3);
}

// ---------------- scatter: emit sorted cloud + permutation ----------------
__global__ __launch_bounds__(256)
void scatter_kernel(const float4* __restrict__ sp, const int* __restrict__ rank,
                    float4* __restrict__ s4, unsigned short* __restrict__ sidx) {
    const int idx = blockIdx.x * 256 + threadIdx.x;   // 0..32767
    const int b = idx >> 12, e = idx & 4095;
    float4 s = sp[idx];
    float w = fmaf(s.x, s.x, fmaf(s.y, s.y, s.z * s.z));
    const int r = rank[idx];
    s4[(b << 12) + r] = make_float4(s.x, s.y, s.z, w);
    sidx[(b << 12) + r] = (unsigned short)e;
}

// ---------------- knn: 8-wave split, dynamic nearest-first chunks ---------
__global__ __launch_bounds__(512, 4)
void knn_kernel(const float4* __restrict__ sp, const float4* __restrict__ s4,
                const unsigned short* __restrict__ sidx, float* __restrict__ td) {
    volatile __shared__ float sT[8][64];   // per-wave k[10] bound per query
    __shared__ float mrg[8][11][64];
    __shared__ int nxt;
    volatile __shared__ int dn[2];         // [0]=right done, [1]=left done

    const int b  = blockIdx.x >> 6;
    const int c0 = blockIdx.x & 63;
    const int tid = threadIdx.x, lane = tid & 63, s = tid >> 6;
    const float4* s4b = s4 + ((size_t)b << 12);
    const float4* spb = sp + ((size_t)b << 12);
    const unsigned short* sib = sidx + (b << 12);

    if (tid == 0) { nxt = 0; dn[0] = 0; dn[1] = 0; }
    sT[s][lane] = __builtin_inff();
    __syncthreads();

    const int qs = (c0 << 6) + lane;
    const float4 q = s4b[qs];
    const float xqlo = __shfl(q.x, 0, 64);
    const float xqhi = __shfl(q.x, 63, 64);

    float k[11];
#pragma unroll
    for (int j = 0; j < 11; ++j) k[j] = __builtin_inff();

    while (true) {
        if (dn[0] && dn[1]) break;
        int p = 0;
        if (lane == 0) p = atomicAdd(&nxt, 1);
        p = __shfl(p, 0, 64);
        if (p >= 2 * NCH) break;               // all chunks exhausted: safety
        int c, isR;
        if (p == 0) { c = c0; isR = 1; }
        else { int kk = (p - 1) >> 1; isR = p & 1; c = isR ? (c0 + kk + 1) : (c0 - kk - 1); }
        if (isR) { if (c >= NCH) { dn[0] = 1; continue; } if (dn[0]) continue; }
        else     { if (c < 0)    { dn[1] = 1; continue; } if (dn[1]) continue; }

        if (p != 0) {
            // shared bound: min over waves (each k[10] >= true t11), max over
            // lanes (wave-uniform), +1 truncation quantum.
            float bnd = sT[0][lane];
#pragma unroll
            for (int w = 1; w < 8; ++w) bnd = fminf(bnd, sT[w][lane]);
#pragma unroll
            for (int o = 32; o > 0; o >>= 1) bnd = fmaxf(bnd, __shfl_xor(bnd, o, 64));
            float T = __uint_as_float(__float_as_uint(bnd) + 0x1000u);
            const int cb0 = c << 6;
            float gap = isR ? (s4b[cb0].x - xqhi) : (xqlo - s4b[cb0 + 63].x);
            if (gap > 0.0f && gap * gap > T) { dn[isR ? 0 : 1] = 1; continue; }
        }

        {
            const int cb = __builtin_amdgcn_readfirstlane(c) << 6;  // uniform
#pragma unroll 8
            for (int i = 0; i < 64; ++i) {
                float4 cc = s4b[cb + i];
                float dot = fmaf(q.x, cc.x, fmaf(q.y, cc.y, q.z * cc.z));
                float d2  = fmaxf(fmaf(-2.0f, dot, q.w + cc.w), 0.0f);
                unsigned u = (__float_as_uint(d2) & 0xFFFFF000u) | (unsigned)(cb + i);
                insert11(k, __uint_as_float(u));
            }
            sT[s][lane] = k[10];
        }
    }

#pragma unroll
    for (int j = 0; j < 11; ++j) mrg[s][j][lane] = k[j];
    __syncthreads();

    if (s == 0) {
#pragma unroll
        for (int sg = 1; sg < 8; ++sg)
#pragma unroll
            for (int j = 0; j < 11; ++j) insert11(k, mrg[sg][j][lane]);

        // k[0] is self (exact d2 == 0 -> key == qs, strictly smallest).
        const int oq = sib[qs];
        const float rn = spb[oq].w;
        float best = 1e30f;
#pragma unroll
        for (int j = 1; j <= 10; ++j) {
            int m = (int)(__float_as_uint(k[j]) & 0xFFFu);
            float4 cc = s4b[m];
            float dx = q.x - cc.x, dy = q.y - cc.y, dz = q.z - cc.z;
            float dis = sqrtf(fmaf(dx, dx, fmaf(dy, dy, dz * dz)));
            float rm = spb[sib[m]].w;
            best = fminf(best, dis - (rn + rm));
        }
        td[(b << 12) + oq] = best;
    }
}

// ---------------- variance (ddof=1), two-pass ----------------
__global__ void var_kernel(const float* __restrict__ td, float* __restrict__ vars) {
    __shared__ float red[256];
    const int b = blockIdx.x, t = threadIdx.x;
    const float* x = td + (b << 12);

    float ssum = 0.0f;
    for (int i = t; i < NN; i += 256) ssum += x[i];
    red[t] = ssum;
    __syncthreads();
    for (int o = 128; o > 0; o >>= 1) {
        if (t < o) red[t] += red[t + o];
        __syncthreads();
    }
    const float mu = red[0] / (float)NN;
    __syncthreads();

    float ss = 0.0f;
    for (int i = t; i < NN; i += 256) {
        float d = x[i] - mu;
        ss = fmaf(d, d, ss);
    }
    red[t] = ss;
    __syncthreads();
    for (int o = 128; o > 0; o >>= 1) {
        if (t < o) red[t] += red[t + o];
        __syncthreads();
    }
    if (t == 0) vars[b] = red[0] / (float)(NN - 1);
}

__global__ void fin_kernel(const float* __restrict__ vars, float* __restrict__ out) {
    if (threadIdx.x == 0) {
        float sum = 0.0f;
        for (int b = 0; b < NB; ++b) sum += vars[b];
        out[0] = sum / (float)NB;
    }
}

extern "C" void kernel_launch(void* const* d_in, const int* in_sizes, int n_in,
                              void* d_out, int out_size, void* d_ws, size_t ws_size,
                              hipStream_t stream) {
    const float4* spheres = (const float4*)d_in[0];
    char* ws = (char*)d_ws;
    float4*          s4   = (float4*)(ws);                        // 512 KB
    unsigned short*  sidx = (unsigned short*)(ws + 512 * 1024);   // 64 KB
    int*             rank = (int*)(ws + 576 * 1024);              // 128 KB
    float*           td   = (float*)(ws + 704 * 1024);            // 128 KB
    float*           vars = (float*)(ws + 832 * 1024);            // 32 B
    float* out = (float*)d_out;

    hipMemsetAsync(rank, 0, NB * NN * sizeof(int), stream);
    rank_kernel<<<dim3(NB * 128), dim3(256), 0, stream>>>(spheres, rank);
    scatter_kernel<<<dim3(NB * NN / 256), dim3(256), 0, stream>>>(spheres, rank, s4, sidx);
    knn_kernel<<<dim3(NB * NCH), dim3(512), 0, stream>>>(spheres, s4, sidx, td);
    var_kernel<<<dim3(NB), dim3(256), 0, stream>>>(td, vars);
    fin_kernel<<<dim3(1), dim3(64), 0, stream>>>(vars, out);
}